// Round 9
// baseline (1009.668 us; speedup 1.0000x reference)
//
#include <hip/hip_runtime.h>
#include <cstdint>
#include <cstddef>

using short8  = __attribute__((ext_vector_type(8))) short;
using floatx4 = __attribute__((ext_vector_type(4))) float;
using floatx2 = __attribute__((ext_vector_type(2))) float;
typedef unsigned short u16;
typedef unsigned char  u8;

constexpr int NN = 30000;   // nodes
constexpr int NE = 60000;   // edges / messages
constexpr int BATCH = 256;
constexpr int VV = 40;
constexpr int NBOND = 4;
constexpr int TT = 6;
constexpr int TB = 3;       // steps per chunk
constexpr int PT = 1536, PA = 1280, PB = 2560;
constexpr int PALL = PT + PA + PB;   // 5376

__device__ __forceinline__ float b2f(u16 h) {
  union { unsigned u; float f; } v; v.u = ((unsigned)h) << 16; return v.f;
}
__device__ __forceinline__ u16 f2b(float f) {
  union { float f; unsigned u; } v; v.f = f;
  unsigned r = v.u + 0x7FFFu + ((v.u >> 16) & 1u);
  return (u16)(r >> 16);
}
__device__ __forceinline__ float lo16(unsigned u) {
  union { unsigned x; float f; } v; v.x = u << 16; return v.f;
}
__device__ __forceinline__ float hi16(unsigned u) {
  union { unsigned x; float f; } v; v.x = u & 0xffff0000u; return v.f;
}
__device__ __forceinline__ unsigned pack2(float a, float b) {
  return ((unsigned)f2b(a)) | (((unsigned)f2b(b)) << 16);
}
// fp8 e4m3 (gfx950 OCP) HW conversions — round-trip internal use only
__device__ __forceinline__ floatx2 f8lo(unsigned v) {
  return __builtin_amdgcn_cvt_pk_f32_fp8((int)v, false);
}
__device__ __forceinline__ floatx2 f8hi(unsigned v) {
  return __builtin_amdgcn_cvt_pk_f32_fp8((int)v, true);
}
__device__ __forceinline__ unsigned pk8(float a, float b, float c, float d) {
  int w = __builtin_amdgcn_cvt_pk_fp8_f32(a, b, 0, false);
  w = __builtin_amdgcn_cvt_pk_fp8_f32(c, d, w, true);
  return (unsigned)w;
}
__device__ __forceinline__ u8 f2f8(float v) {
  return (u8)(__builtin_amdgcn_cvt_pk_fp8_f32(v, v, 0, false) & 0xff);
}

// ---------------------------------------------------------------------------
// FUSED gather + GEMM (the depth-chain workhorse):
//   row r in [0,Mtot): tl=r/NE, e=r-tl*NE
//   A(r) = relu(pre[e] + sum_j tab[sidx(r,j)] + b_h), 0 if e==0   (fp8 domain)
//   C[r] = A(r) @ B        (bf16 MFMA, C fp8)
// The gathered A tile (128x256 fp8) is staged into LDS ONCE per block
// (single scatter phase, all loads in flight); the K-loop reads A from LDS
// and stages only the small L2-hot B chunk per iteration.
// 512 threads, 128x256 tile. LDS = 33.8K(A) + 20.5K(B) + 3K(idx) = 56 KB.
// ---------------------------------------------------------------------------
template<int SHARED_TAB>
__global__ __launch_bounds__(512) void fused_gg_kernel(
    const u8* __restrict__ tab, const u8* __restrict__ pre,
    const int* __restrict__ bgraph, const int* __restrict__ emask,
    const float* __restrict__ bias, int t0, int Mtot,
    const u16* __restrict__ Bt, u8* __restrict__ C)
{
  __shared__ __align__(16) u8  As8[128][264];   // fp8, pitch 264 (8B-aligned)
  __shared__ __align__(16) u16 Bs[256][40];
  __shared__ int sidx[128][6];
  const int tid = threadIdx.x;
  const int rowbase = blockIdx.x * 128;

  // indices (emask folded)
  for (int i = tid; i < 768; i += 512) {
    int r = i / 6, j = i - r * 6;
    int grow = rowbase + r;
    int v = 0;
    if (grow < Mtot) {
      int tl = grow / NE;
      int e = grow - tl * NE;
      v = bgraph[(long)e * 6 + j];
      v = v * emask[(long)(t0 + tl) * NE + v];
      if (!SHARED_TAB) v += tl * NE;
    }
    sidx[r][j] = v;
  }
  __syncthreads();

  // gather-stage A: thread -> row tid>>2, 8 chunks of 8B (4 lanes consecutive)
  {
    int r = tid >> 2;
    int grow = rowbase + r;
    int tl = (grow < Mtot) ? (grow / NE) : 0;
    int e = grow - tl * NE;
    bool valid = (grow < Mtot) && (e > 0);
    const u8* prow = pre + (long)e * 256;
    int i0 = sidx[r][0], i1 = sidx[r][1], i2 = sidx[r][2];
    int i3 = sidx[r][3], i4 = sidx[r][4], i5 = sidx[r][5];
#pragma unroll
    for (int ch = 0; ch < 8; ch++) {
      int c = (tid & 3) * 8 + ch * 32;
      float a0 = 0.f, a1 = 0.f, a2 = 0.f, a3 = 0.f;
      float a4 = 0.f, a5 = 0.f, a6 = 0.f, a7 = 0.f;
      if (valid) {
        uint2 p = *(const uint2*)(prow + c);
        floatx2 p0 = f8lo(p.x), p1 = f8hi(p.x), p2 = f8lo(p.y), p3 = f8hi(p.y);
        a0 = p0.x; a1 = p0.y; a2 = p1.x; a3 = p1.y;
        a4 = p2.x; a5 = p2.y; a6 = p3.x; a7 = p3.y;
#define GACC(ii) { uint2 g = *(const uint2*)(tab + (long)(ii) * 256 + c);              \
        floatx2 g0 = f8lo(g.x), g1 = f8hi(g.x), g2 = f8lo(g.y), g3 = f8hi(g.y);        \
        a0 += g0.x; a1 += g0.y; a2 += g1.x; a3 += g1.y;                                \
        a4 += g2.x; a5 += g2.y; a6 += g3.x; a7 += g3.y; }
        GACC(i0) GACC(i1) GACC(i2) GACC(i3) GACC(i4) GACC(i5)
#undef GACC
        float4 b0 = *(const float4*)(bias + c);
        float4 b1 = *(const float4*)(bias + c + 4);
        a0 = fmaxf(a0 + b0.x, 0.f); a1 = fmaxf(a1 + b0.y, 0.f);
        a2 = fmaxf(a2 + b0.z, 0.f); a3 = fmaxf(a3 + b0.w, 0.f);
        a4 = fmaxf(a4 + b1.x, 0.f); a5 = fmaxf(a5 + b1.y, 0.f);
        a6 = fmaxf(a6 + b1.z, 0.f); a7 = fmaxf(a7 + b1.w, 0.f);
      }
      uint2 o; o.x = pk8(a0, a1, a2, a3); o.y = pk8(a4, a5, a6, a7);
      *(uint2*)(&As8[r][c]) = o;
    }
  }
  __syncthreads();

  const int wave = tid >> 6, lane = tid & 63;
  const int wm = wave >> 2, wn = wave & 3;
  const int lr = lane & 15, lk = (lane >> 4) * 8;
  const int brow = tid >> 1, bc16 = (tid & 1) * 16;

  floatx4 acc[4][4];
#pragma unroll
  for (int i = 0; i < 4; i++)
#pragma unroll
    for (int j = 0; j < 4; j++) acc[i][j] = {0.f, 0.f, 0.f, 0.f};

  for (int k0 = 0; k0 < 256; k0 += 32) {
    // stage B chunk (L2-hot, 16 KB): two uint4 writes cover all 32 u16 cols
    *(uint4*)(&Bs[brow][bc16]) = *(const uint4*)(Bt + (long)brow * 256 + k0 + bc16);
    *(uint4*)(&Bs[brow][bc16 + 8]) = *(const uint4*)(Bt + (long)brow * 256 + k0 + bc16 + 8);
    __syncthreads();
    short8 af[4], bf[4];
#pragma unroll
    for (int mt = 0; mt < 4; mt++) {
      uint2 v8 = *(const uint2*)(&As8[wm * 64 + mt * 16 + lr][k0 + lk]);
      floatx2 f0 = f8lo(v8.x), f1 = f8hi(v8.x), f2 = f8lo(v8.y), f3 = f8hi(v8.y);
      union { unsigned u[4]; short8 s; } cv;
      cv.u[0] = pack2(f0.x, f0.y); cv.u[1] = pack2(f1.x, f1.y);
      cv.u[2] = pack2(f2.x, f2.y); cv.u[3] = pack2(f3.x, f3.y);
      af[mt] = cv.s;
    }
#pragma unroll
    for (int nt = 0; nt < 4; nt++) bf[nt] = *(const short8*)(&Bs[wn * 64 + nt * 16 + lr][lk]);
#pragma unroll
    for (int mt = 0; mt < 4; mt++)
#pragma unroll
      for (int nt = 0; nt < 4; nt++)
        acc[mt][nt] = __builtin_amdgcn_mfma_f32_16x16x32_bf16(af[mt], bf[nt], acc[mt][nt], 0, 0, 0);
    __syncthreads();
  }

  const int rq = (lane >> 4) * 4;
#pragma unroll
  for (int mt = 0; mt < 4; mt++) {
#pragma unroll
    for (int nt = 0; nt < 4; nt++) {
      int gcol = wn * 64 + nt * 16 + lr;
#pragma unroll
      for (int r2 = 0; r2 < 4; r2++) {
        int grow = rowbase + wm * 64 + mt * 16 + rq + r2;
        if (grow < Mtot) C[(long)grow * 256 + gcol] = f2f8(acc[mt][nt][r2]);
      }
    }
  }
}

// ---------------------------------------------------------------------------
// Full-N GEMM for precomputes: C[M,256] = A[M,256] @ B, 128x256, 512 threads.
// AMODE 1: A f32   AMODE 2: A fp8; staged = relu(A + abias); row 0 -> 0
// OMODE 0: C bf16  OMODE 1: C fp8
// ---------------------------------------------------------------------------
template<int AMODE, int OMODE>
__global__ __launch_bounds__(512) void gemm_n256_kernel(
    const void* __restrict__ Av, int M,
    const u16* __restrict__ Bt,
    void* __restrict__ Cv, const float* __restrict__ abias)
{
  __shared__ __align__(16) u16 As[128][40];
  __shared__ __align__(16) u16 Bs[256][40];
  const int tid = threadIdx.x;
  const int rowbase = blockIdx.x * 128;
  const int wave = tid >> 6, lane = tid & 63;
  const int wm = wave >> 2, wn = wave & 3;
  const int lr = lane & 15, lk = (lane >> 4) * 8;
  const int arow = tid >> 2, ac8 = (tid & 3) * 8;
  const int brow = tid >> 1, bc16 = (tid & 1) * 16;

  floatx4 acc[4][4];
#pragma unroll
  for (int i = 0; i < 4; i++)
#pragma unroll
    for (int j = 0; j < 4; j++) acc[i][j] = {0.f, 0.f, 0.f, 0.f};

  for (int k0 = 0; k0 < 256; k0 += 32) {
    {
      int grow = rowbase + arow;
      uint4 av = {0u, 0u, 0u, 0u};
      if (AMODE == 1) {
        if (grow < M) {
          const float* Af = (const float*)Av;
          float4 f0 = *(const float4*)(Af + (long)grow * 256 + k0 + ac8);
          float4 f1 = *(const float4*)(Af + (long)grow * 256 + k0 + ac8 + 4);
          av.x = pack2(f0.x, f0.y); av.y = pack2(f0.z, f0.w);
          av.z = pack2(f1.x, f1.y); av.w = pack2(f1.z, f1.w);
        }
      } else {
        if (grow < M) {
          const u8* Af8 = (const u8*)Av;
          uint2 v8 = *(const uint2*)(Af8 + (long)grow * 256 + k0 + ac8);
          floatx2 f0 = f8lo(v8.x), f1 = f8hi(v8.x), f2 = f8lo(v8.y), f3 = f8hi(v8.y);
          float a0 = f0.x, a1 = f0.y, a2 = f1.x, a3 = f1.y;
          float a4 = f2.x, a5 = f2.y, a6 = f3.x, a7 = f3.y;
          if (grow == 0) { a0 = a1 = a2 = a3 = a4 = a5 = a6 = a7 = 0.f; }
          else {
            float4 b0 = *(const float4*)(abias + k0 + ac8);
            float4 b1 = *(const float4*)(abias + k0 + ac8 + 4);
            a0 = fmaxf(a0 + b0.x, 0.f); a1 = fmaxf(a1 + b0.y, 0.f);
            a2 = fmaxf(a2 + b0.z, 0.f); a3 = fmaxf(a3 + b0.w, 0.f);
            a4 = fmaxf(a4 + b1.x, 0.f); a5 = fmaxf(a5 + b1.y, 0.f);
            a6 = fmaxf(a6 + b1.z, 0.f); a7 = fmaxf(a7 + b1.w, 0.f);
          }
          av.x = pack2(a0, a1); av.y = pack2(a2, a3);
          av.z = pack2(a4, a5); av.w = pack2(a6, a7);
        }
      }
      *(uint4*)(&As[arow][ac8]) = av;
      uint4 v0 = *(const uint4*)(Bt + (long)brow * 256 + k0 + bc16);
      uint4 v1 = *(const uint4*)(Bt + (long)brow * 256 + k0 + bc16 + 8);
      *(uint4*)(&Bs[brow][bc16]) = v0;
      *(uint4*)(&Bs[brow][bc16 + 8]) = v1;
    }
    __syncthreads();
    short8 af[4], bf[4];
#pragma unroll
    for (int mt = 0; mt < 4; mt++) af[mt] = *(const short8*)(&As[wm * 64 + mt * 16 + lr][lk]);
#pragma unroll
    for (int nt = 0; nt < 4; nt++) bf[nt] = *(const short8*)(&Bs[wn * 64 + nt * 16 + lr][lk]);
#pragma unroll
    for (int mt = 0; mt < 4; mt++)
#pragma unroll
      for (int nt = 0; nt < 4; nt++)
        acc[mt][nt] = __builtin_amdgcn_mfma_f32_16x16x32_bf16(af[mt], bf[nt], acc[mt][nt], 0, 0, 0);
    __syncthreads();
  }

  const int rq = (lane >> 4) * 4;
#pragma unroll
  for (int mt = 0; mt < 4; mt++) {
#pragma unroll
    for (int nt = 0; nt < 4; nt++) {
      int gcol = wn * 64 + nt * 16 + lr;
#pragma unroll
      for (int r2 = 0; r2 < 4; r2++) {
        int grow = rowbase + wm * 64 + mt * 16 + rq + r2;
        if (grow < M) {
          float v = acc[mt][nt][r2];
          if (OMODE == 0) ((u16*)Cv)[(long)grow * 256 + gcol] = f2b(v);
          else            ((u8*)Cv)[(long)grow * 256 + gcol] = f2f8(v);
        }
      }
    }
  }
}

// ---------------------------------------------------------------------------
// 128x128-tile GEMM for head matrices. MODE 0: plain  MODE 1: relu+bias
// ---------------------------------------------------------------------------
template<int MODE>
__global__ __launch_bounds__(256) void gemm_bt_kernel(
    const u16* __restrict__ A, int lda, int M,
    const u16* __restrict__ Bt, int K,
    u16* __restrict__ C, int ldc, const float* __restrict__ bias)
{
  __shared__ __align__(16) u16 As[128][56];
  __shared__ __align__(16) u16 Bs[128][56];
  const int tid  = threadIdx.x;
  const int wave = tid >> 6, lane = tid & 63;
  const int wm = wave >> 1, wn = wave & 1;
  const int lr = lane & 15, lk = (lane >> 4) * 8;
  const int rowbase = blockIdx.x * 128;
  const int colbase = blockIdx.y * 128;

  floatx4 acc[4][4];
#pragma unroll
  for (int i = 0; i < 4; i++)
#pragma unroll
    for (int j = 0; j < 4; j++) acc[i][j] = {0.f, 0.f, 0.f, 0.f};

  for (int k0 = 0; k0 < K; k0 += 32) {
#pragma unroll
    for (int r = 0; r < 2; r++) {
      int c = tid + 256 * r;
      int row = c >> 2, cc = (c & 3) * 8;
      int grow = rowbase + row;
      uint4 av = {0u, 0u, 0u, 0u};
      if (grow < M) av = *(const uint4*)(A + (long)grow * lda + k0 + cc);
      *(uint4*)(&As[row][cc]) = av;
      uint4 bv = *(const uint4*)(Bt + (long)(colbase + row) * K + k0 + cc);
      *(uint4*)(&Bs[row][cc]) = bv;
    }
    __syncthreads();
    short8 af[4], bf[4];
#pragma unroll
    for (int mt = 0; mt < 4; mt++) af[mt] = *(const short8*)(&As[wm * 64 + mt * 16 + lr][lk]);
#pragma unroll
    for (int nt = 0; nt < 4; nt++) bf[nt] = *(const short8*)(&Bs[wn * 64 + nt * 16 + lr][lk]);
#pragma unroll
    for (int mt = 0; mt < 4; mt++)
#pragma unroll
      for (int nt = 0; nt < 4; nt++)
        acc[mt][nt] = __builtin_amdgcn_mfma_f32_16x16x32_bf16(af[mt], bf[nt], acc[mt][nt], 0, 0, 0);
    __syncthreads();
  }

  const int rq = (lane >> 4) * 4;
#pragma unroll
  for (int mt = 0; mt < 4; mt++) {
#pragma unroll
    for (int nt = 0; nt < 4; nt++) {
      int gcol = colbase + wn * 64 + nt * 16 + lr;
#pragma unroll
      for (int r2 = 0; r2 < 4; r2++) {
        int grow = rowbase + wm * 64 + mt * 16 + rq + r2;
        if (grow < M) {
          float v = acc[mt][nt][r2];
          if (MODE == 1) { v += bias[gcol]; v = v > 0.f ? v : 0.f; }
          C[(long)grow * ldc + gcol] = f2b(v);
        }
      }
    }
  }
}

// Merged topo+atom head GEMM (K=544): rowbase<PT -> (Bt1,b1) else (Bt2,b2)
__global__ __launch_bounds__(256) void gemm_ta_kernel(
    const u16* __restrict__ A,
    const u16* __restrict__ Bt1, const u16* __restrict__ Bt2,
    const float* __restrict__ b1, const float* __restrict__ b2,
    u16* __restrict__ C)
{
  constexpr int K = 544;
  __shared__ __align__(16) u16 As[128][56];
  __shared__ __align__(16) u16 Bs[128][56];
  const int tid  = threadIdx.x;
  const int wave = tid >> 6, lane = tid & 63;
  const int wm = wave >> 1, wn = wave & 1;
  const int lr = lane & 15, lk = (lane >> 4) * 8;
  const int rowbase = blockIdx.x * 128;
  const int colbase = blockIdx.y * 128;
  const u16* Bt = (rowbase < PT) ? Bt1 : Bt2;
  const float* bias = (rowbase < PT) ? b1 : b2;

  floatx4 acc[4][4];
#pragma unroll
  for (int i = 0; i < 4; i++)
#pragma unroll
    for (int j = 0; j < 4; j++) acc[i][j] = {0.f, 0.f, 0.f, 0.f};

  for (int k0 = 0; k0 < K; k0 += 32) {
#pragma unroll
    for (int r = 0; r < 2; r++) {
      int c = tid + 256 * r;
      int row = c >> 2, cc = (c & 3) * 8;
      int grow = rowbase + row;
      uint4 av = *(const uint4*)(A + (long)grow * K + k0 + cc);
      *(uint4*)(&As[row][cc]) = av;
      uint4 bv = *(const uint4*)(Bt + (long)(colbase + row) * K + k0 + cc);
      *(uint4*)(&Bs[row][cc]) = bv;
    }
    __syncthreads();
    short8 af[4], bf[4];
#pragma unroll
    for (int mt = 0; mt < 4; mt++) af[mt] = *(const short8*)(&As[wm * 64 + mt * 16 + lr][lk]);
#pragma unroll
    for (int nt = 0; nt < 4; nt++) bf[nt] = *(const short8*)(&Bs[wn * 64 + nt * 16 + lr][lk]);
#pragma unroll
    for (int mt = 0; mt < 4; mt++)
#pragma unroll
      for (int nt = 0; nt < 4; nt++)
        acc[mt][nt] = __builtin_amdgcn_mfma_f32_16x16x32_bf16(af[mt], bf[nt], acc[mt][nt], 0, 0, 0);
    __syncthreads();
  }

  const int rq = (lane >> 4) * 4;
#pragma unroll
  for (int mt = 0; mt < 4; mt++) {
#pragma unroll
    for (int nt = 0; nt < 4; nt++) {
      int gcol = colbase + wn * 64 + nt * 16 + lr;
#pragma unroll
      for (int r2 = 0; r2 < 4; r2++) {
        int grow = rowbase + wm * 64 + mt * 16 + rq + r2;
        float v = acc[mt][nt][r2] + bias[gcol];
        v = v > 0.f ? v : 0.f;
        C[(long)grow * 256 + gcol] = f2b(v);
      }
    }
  }
}

// Logits GEMM: L[5376,64] = hid_all @ w2c[seg] + b2c[seg]   (f32 out)
__global__ __launch_bounds__(256) void gemm_logits_kernel(
    const u16* __restrict__ A, const u16* __restrict__ w2c,
    const float* __restrict__ b2c, float* __restrict__ L)
{
  __shared__ __align__(16) u16 As[128][40];
  __shared__ __align__(16) u16 Bs[64][40];
  const int tid = threadIdx.x;
  const int rowbase = blockIdx.x * 128;
  const int seg = (rowbase < PT) ? 0 : (rowbase < PT + PA ? 1 : 2);
  const u16* Bt = w2c + seg * 64 * 256;
  const int wave = tid >> 6, lane = tid & 63;
  const int wm = wave >> 1, wn = wave & 1;
  const int lr = lane & 15, lk = (lane >> 4) * 8;
  const int sr = tid >> 2, sc = (tid & 3) * 8;

  floatx4 acc[4][2];
#pragma unroll
  for (int i = 0; i < 4; i++)
#pragma unroll
    for (int j = 0; j < 2; j++) acc[i][j] = {0.f, 0.f, 0.f, 0.f};

  for (int k0 = 0; k0 < 256; k0 += 32) {
    *(uint4*)(&As[sr][sc]) = *(const uint4*)(A + (long)(rowbase + sr) * 256 + k0 + sc);
    *(uint4*)(&As[sr + 64][sc]) = *(const uint4*)(A + (long)(rowbase + sr + 64) * 256 + k0 + sc);
    *(uint4*)(&Bs[sr][sc]) = *(const uint4*)(Bt + (long)sr * 256 + k0 + sc);
    __syncthreads();
    short8 af[4], bf[2];
#pragma unroll
    for (int mt = 0; mt < 4; mt++) af[mt] = *(const short8*)(&As[wm * 64 + mt * 16 + lr][lk]);
#pragma unroll
    for (int nt = 0; nt < 2; nt++) bf[nt] = *(const short8*)(&Bs[wn * 32 + nt * 16 + lr][lk]);
#pragma unroll
    for (int mt = 0; mt < 4; mt++)
#pragma unroll
      for (int nt = 0; nt < 2; nt++)
        acc[mt][nt] = __builtin_amdgcn_mfma_f32_16x16x32_bf16(af[mt], bf[nt], acc[mt][nt], 0, 0, 0);
    __syncthreads();
  }

  const int rq = (lane >> 4) * 4;
#pragma unroll
  for (int mt = 0; mt < 4; mt++) {
#pragma unroll
    for (int nt = 0; nt < 2; nt++) {
      int gcol = wn * 32 + nt * 16 + lr;
#pragma unroll
      for (int r2 = 0; r2 < 4; r2++) {
        int grow = rowbase + wm * 64 + mt * 16 + rq + r2;
        L[(long)grow * 64 + gcol] = acc[mt][nt][r2] + b2c[seg * 64 + gcol];
      }
    }
  }
}

// build combined second-layer weights (bf16, Bt layout) + biases
__global__ __launch_bounds__(256) void build_w2c_kernel(
    const float* __restrict__ tw2, const float* __restrict__ tb2,
    const float* __restrict__ aw2, const float* __restrict__ ab2,
    const float* __restrict__ bw2, const float* __restrict__ bb2,
    u16* __restrict__ w2c, float* __restrict__ b2c)
{
  int idx = blockIdx.x * 256 + threadIdx.x;
  int seg = idx / 16384;
  int rem = idx - seg * 16384;
  int n = rem >> 8, k = rem & 255;
  const float* W; int NC;
  if (seg == 0)      { W = tw2; NC = 1; }
  else if (seg == 1) { W = aw2; NC = VV; }
  else               { W = bw2; NC = NBOND; }
  w2c[idx] = (n < NC) ? f2b(W[(long)k * NC + n]) : (u16)0;
  if (idx < 192) {
    int s2 = idx / 64, n2 = idx & 63;
    const float* B2 = (s2 == 0) ? tb2 : (s2 == 1 ? ab2 : bb2);
    int NC2 = (s2 == 0) ? 1 : (s2 == 1 ? VV : NBOND);
    b2c[idx] = (n2 < NC2) ? B2[n2] : 0.f;
  }
}

// final loss from logits: 1344 blocks x 4 rows; one atomic per block
__global__ __launch_bounds__(256) void loss_finalize_kernel(
    const float* __restrict__ L,
    const int* __restrict__ tlab, const int* __restrict__ alab,
    const int* __restrict__ blab, float* __restrict__ out)
{
  __shared__ float part[4];
  int wave = threadIdx.x >> 6, lane = threadIdx.x & 63;
  int r = blockIdx.x * 4 + wave;
  float contrib = 0.f;
  if (r < PT) {
    float l = L[(long)r * 64];
    float y = (float)tlab[r];
    contrib = fmaxf(l, 0.f) + log1pf(expf(-fabsf(l))) - l * y;
  } else {
    int NC, lb;
    if (r < PT + PA) { NC = VV; lb = alab[r - PT]; }
    else             { NC = NBOND; lb = blab[r - PT - PA]; }
    bool valid = lane < NC;
    float logit = valid ? L[(long)r * 64 + lane] : -1e30f;
    float m = logit;
#pragma unroll
    for (int off = 32; off > 0; off >>= 1) m = fmaxf(m, __shfl_xor(m, off));
    float e = valid ? expf(logit - m) : 0.f;
#pragma unroll
    for (int off = 32; off > 0; off >>= 1) e += __shfl_xor(e, off);
    float lse = m + logf(e);
    float ll = __shfl(logit, lb);
    contrib = lse - ll;
  }
  if (lane == 0) part[wave] = contrib;
  __syncthreads();
  if (threadIdx.x == 0)
    atomicAdd(out, (part[0] + part[1] + part[2] + part[3]) * (1.0f / BATCH));
}

// node gather over TB steps: node[r](bf16) = relu(fo[n] + sum_j T[tl*NE+ag*em](fp8) + b_o)*vm
__global__ __launch_bounds__(256) void gather_n2_kernel(
    const u8* __restrict__ tab, const u16* __restrict__ fo,
    const int* __restrict__ agraph, const int* __restrict__ emask,
    const float* __restrict__ bias, const int* __restrict__ vmask,
    int t0, u16* __restrict__ node)
{
  int r0 = blockIdx.x * 8;
  int tl = r0 / NN;
  int n0 = r0 - tl * NN;
  const int* em_t = emask + (long)(t0 + tl) * NE;
  const int* vm_t = vmask + (long)(t0 + tl) * NN;
  __shared__ int sidx[8][6];
  __shared__ int svm[8];
  int tid = threadIdx.x;
  if (tid < 48) {
    int rr = tid / 6, j = tid - rr * 6;
    int v = agraph[(long)(n0 + rr) * 6 + j];
    sidx[rr][j] = tl * NE + v * em_t[v];
  }
  if (tid >= 48 && tid < 56) svm[tid - 48] = vm_t[n0 + (tid - 48)];
  __syncthreads();
  int rl = tid >> 5, ch = (tid & 31) * 8;
  int n = n0 + rl;
  uint4 p = *(const uint4*)(fo + (long)n * 256 + ch);
  float a0 = lo16(p.x), a1 = hi16(p.x), a2 = lo16(p.y), a3 = hi16(p.y);
  float a4 = lo16(p.z), a5 = hi16(p.z), a6 = lo16(p.w), a7 = hi16(p.w);
#pragma unroll
  for (int j = 0; j < 6; j++) {
    uint2 g = *(const uint2*)(tab + (long)sidx[rl][j] * 256 + ch);
    floatx2 g0 = f8lo(g.x), g1 = f8hi(g.x), g2 = f8lo(g.y), g3 = f8hi(g.y);
    a0 += g0.x; a1 += g0.y; a2 += g1.x; a3 += g1.y;
    a4 += g2.x; a5 += g2.y; a6 += g3.x; a7 += g3.y;
  }
  float4 b0 = *(const float4*)(bias + ch);
  float4 b1 = *(const float4*)(bias + ch + 4);
  a0 = fmaxf(a0 + b0.x, 0.f); a1 = fmaxf(a1 + b0.y, 0.f);
  a2 = fmaxf(a2 + b0.z, 0.f); a3 = fmaxf(a3 + b0.w, 0.f);
  a4 = fmaxf(a4 + b1.x, 0.f); a5 = fmaxf(a5 + b1.y, 0.f);
  a6 = fmaxf(a6 + b1.z, 0.f); a7 = fmaxf(a7 + b1.w, 0.f);
  if (svm[rl] == 0) { a0 = a1 = a2 = a3 = a4 = a5 = a6 = a7 = 0.f; }
  uint4 o; o.x = pack2(a0, a1); o.y = pack2(a2, a3); o.z = pack2(a4, a5); o.w = pack2(a6, a7);
  *(uint4*)(node + (long)(r0 + rl) * 256 + ch) = o;
}

// zero gvec + out
__global__ __launch_bounds__(256) void init_zero_kernel(float* __restrict__ gv,
                                                        float* __restrict__ out)
{
  int i = blockIdx.x * 256 + threadIdx.x;
  gv[i] = 0.f;
  if (i == 0) out[0] = 0.f;
}

// all 9 first-layer weight transposes in one dispatch
__global__ __launch_bounds__(256) void transpose_all_kernel(
    const float* W_h, const float* U_h, const float* W_o,
    const float* tw1, const float* aw1, const float* bw1,
    const float* rw, const float* ww,
    u16* Wh_t, u16* Uh_t, u16* Wo1_t, u16* Wo2_t,
    u16* tw1_t, u16* aw1_t, u16* bw1_t, u16* rw_t, u16* ww_t)
{
  int b = blockIdx.x;
  const float* W; int K, Kpad; u16* Bt; int base;
  if      (b < 256)  { W = W_h;  K = 256; Kpad = 256; Bt = Wh_t;  base = 0; }
  else if (b < 512)  { W = U_h;  K = 256; Kpad = 256; Bt = Uh_t;  base = 256; }
  else if (b < 768)  { W = W_o;  K = 256; Kpad = 256; Bt = Wo1_t; base = 512; }
  else if (b < 1024) { W = W_o + 256 * 256; K = 256; Kpad = 256; Bt = Wo2_t; base = 768; }
  else if (b < 1568) { W = tw1;  K = 544; Kpad = 544; Bt = tw1_t; base = 1024; }
  else if (b < 2112) { W = aw1;  K = 544; Kpad = 544; Bt = aw1_t; base = 1568; }
  else if (b < 2912) { W = bw1;  K = 800; Kpad = 800; Bt = bw1_t; base = 2112; }
  else if (b < 3232) { W = rw;   K = 296; Kpad = 320; Bt = rw_t;  base = 2912; }
  else               { W = ww;   K = 260; Kpad = 288; Bt = ww_t;  base = 3232; }
  int idx = (b - base) * 256 + threadIdx.x;
  int n = idx / Kpad, k = idx - n * Kpad;
  Bt[idx] = (k < K) ? f2b(W[(long)k * 256 + n]) : (u16)0;
}

// combined: blocks [0,938*TB) gvec segmented-sum; rest: head scatter
__global__ __launch_bounds__(256) void gvec_head_kernel(int t0,
    const u16* __restrict__ node, const int* __restrict__ n2g,
    float* __restrict__ gv,
    const int* __restrict__ tstep, const int* __restrict__ txid,
    const int* __restrict__ astep, const int* __restrict__ axid,
    const int* __restrict__ bstep, const int* __restrict__ bzid,
    u16* __restrict__ tv, u16* __restrict__ av, u16* __restrict__ bv,
    u16* __restrict__ wbin)
{
  int b = blockIdx.x;
  constexpr int GVB = 938 * TB;
  if (b < GVB) {
    int tl = b / 938;
    int r0 = (b - tl * 938) * 32;
    if (r0 >= NN) return;
    int h = threadIdx.x;
    const u16* nd = node + (long)tl * NN * 256;
    float* gb = gv + (long)(t0 + tl) * BATCH * 256;
    int rend = r0 + 32; if (rend > NN) rend = NN;
    int gprev = n2g[r0];
    float acc = 0.f;
    for (int r = r0; r < rend; r++) {
      int g = n2g[r];
      if (g != gprev) { atomicAdd(gb + gprev * 256 + h, acc); acc = 0.f; gprev = g; }
      acc += b2f(nd[(long)r * 256 + h]);
    }
    atomicAdd(gb + gprev * 256 + h, acc);
    return;
  }
  int wave = threadIdx.x >> 6, lane = threadIdx.x & 63;
  int r = (b - GVB) * 4 + wave;
  int c = lane * 4;
  if (r < PT) {
    int st = tstep[r];
    if (st < t0 || st >= t0 + TB) return;
    ushort4 v = *(const ushort4*)(node + ((long)(st - t0) * NN + txid[r]) * 256 + c);
    *(ushort4*)(tv + (long)r * 544 + 256 + c) = v;
  } else if (r < PT + PA) {
    int i = r - PT;
    int st = astep[i];
    if (st < t0 || st >= t0 + TB) return;
    ushort4 v = *(const ushort4*)(node + ((long)(st - t0) * NN + axid[i]) * 256 + c);
    *(ushort4*)(av + (long)i * 544 + 256 + c) = v;
  } else if (r < PALL) {
    int i = r - PT - PA;
    int st = bstep[i];
    if (st < t0 || st >= t0 + TB) return;
    ushort4 v = *(const ushort4*)(node + ((long)(st - t0) * NN + bzid[i]) * 256 + c);
    *(ushort4*)(bv + (long)i * 800 + 512 + c) = v;
    *(ushort4*)(wbin + (long)i * 288 + c) = v;
  }
}

// fill gvec / src / one-hot segments of head inputs (after all steps)
__global__ __launch_bounds__(256) void build_static_kernel(
    const float* __restrict__ gvec, const float* __restrict__ src,
    const int* __restrict__ tstep, const int* __restrict__ tbid,
    const int* __restrict__ astep, const int* __restrict__ abid,
    const int* __restrict__ bstep, const int* __restrict__ bbid,
    const int* __restrict__ blabel, const int* __restrict__ batype,
    u16* __restrict__ tv, u16* __restrict__ av, u16* __restrict__ bv,
    u16* __restrict__ wbin, u16* __restrict__ rbin)
{
  int wave = threadIdx.x >> 6, lane = threadIdx.x & 63;
  int r = blockIdx.x * 4 + wave;
  int c = lane * 4;
  if (r < PT) {
    int st = tstep[r], bid = tbid[r];
    const float* g = gvec + ((long)st * BATCH + bid) * 256;
    u16* d = tv + (long)r * 544;
    float4 g4 = *(const float4*)(g + c);
    d[c] = f2b(g4.x); d[c + 1] = f2b(g4.y); d[c + 2] = f2b(g4.z); d[c + 3] = f2b(g4.w);
    if (lane < 8) {
      float4 s4 = *(const float4*)(src + bid * 32 + c);
      d[512 + c] = f2b(s4.x); d[512 + c + 1] = f2b(s4.y);
      d[512 + c + 2] = f2b(s4.z); d[512 + c + 3] = f2b(s4.w);
    }
  } else if (r < PT + PA) {
    int i = r - PT;
    int st = astep[i], bid = abid[i];
    const float* g = gvec + ((long)st * BATCH + bid) * 256;
    u16* d = av + (long)i * 544;
    float4 g4 = *(const float4*)(g + c);
    d[c] = f2b(g4.x); d[c + 1] = f2b(g4.y); d[c + 2] = f2b(g4.z); d[c + 3] = f2b(g4.w);
    if (lane < 8) {
      float4 s4 = *(const float4*)(src + bid * 32 + c);
      d[512 + c] = f2b(s4.x); d[512 + c + 1] = f2b(s4.y);
      d[512 + c + 2] = f2b(s4.z); d[512 + c + 3] = f2b(s4.w);
    }
  } else if (r < PALL) {
    int i = r - PT - PA;
    int st = bstep[i], bid = bbid[i];
    const float* g = gvec + ((long)st * BATCH + bid) * 256;
    u16* d = bv + (long)i * 800;
    float4 g4 = *(const float4*)(g + c);
    d[c] = f2b(g4.x); d[c + 1] = f2b(g4.y); d[c + 2] = f2b(g4.z); d[c + 3] = f2b(g4.w);
    if (lane < 8) {
      float4 s4 = *(const float4*)(src + bid * 32 + c);
      d[768 + c] = f2b(s4.x); d[768 + c + 1] = f2b(s4.y);
      d[768 + c + 2] = f2b(s4.z); d[768 + c + 3] = f2b(s4.w);
      int bl = blabel[i];
      u16* wd = wbin + (long)i * 288 + 256;
      for (int q = 0; q < 4; q++) {
        int k = c + q;
        wd[k] = f2b((k < NBOND && bl == k) ? 1.f : 0.f);
      }
    }
    if (lane < 16) {
      int at = batype[i];
      u16* rd = rbin + (long)i * 320 + 256;
      for (int q = 0; q < 4; q++) {
        int k = c + q;
        rd[k] = f2b((k < VV && at == k) ? 1.f : 0.f);
      }
    }
  }
}

// rbin[r][0:256] = sum_{j in [gs[r], r)} wb[j] * (blabel[j] > 0)
__global__ __launch_bounds__(256) void hist_kernel(
    const u16* __restrict__ wb, const int* __restrict__ gs_arr,
    const int* __restrict__ blabel, u16* __restrict__ rbin)
{
  int wave = threadIdx.x >> 6, lane = threadIdx.x & 63;
  int r = blockIdx.x * 4 + wave;
  if (r >= PB) return;
  int c = lane * 4;
  float a0 = 0.f, a1 = 0.f, a2 = 0.f, a3 = 0.f;
  int gs = gs_arr[r];
  for (int j = gs; j < r; j++) {
    if (blabel[j] > 0) {
      ushort4 g = *(const ushort4*)(wb + (long)j * 256 + c);
      a0 += b2f(g.x); a1 += b2f(g.y); a2 += b2f(g.z); a3 += b2f(g.w);
    }
  }
  u16* rd = rbin + (long)r * 320;
  rd[c] = f2b(a0); rd[c + 1] = f2b(a1); rd[c + 2] = f2b(a2); rd[c + 3] = f2b(a3);
}

// ---------------------------------------------------------------------------
extern "C" void kernel_launch(void* const* d_in, const int* in_sizes, int n_in,
                              void* d_out, int out_size, void* d_ws, size_t ws_size,
                              hipStream_t stream)
{
  const float* src      = (const float*)d_in[0];
  const float* fnode    = (const float*)d_in[1];
  const float* fmess    = (const float*)d_in[2];
  const float* W_h      = (const float*)d_in[3];
  const float* U_h      = (const float*)d_in[4];
  const float* b_h      = (const float*)d_in[5];
  const float* W_o      = (const float*)d_in[6];
  const float* b_o      = (const float*)d_in[7];
  const float* topo_w1  = (const float*)d_in[8];
  const float* topo_b1  = (const float*)d_in[9];
  const float* topo_w2  = (const float*)d_in[10];
  const float* topo_b2  = (const float*)d_in[11];
  const float* atom_w1  = (const float*)d_in[12];
  const float* atom_b1  = (const float*)d_in[13];
  const float* atom_w2  = (const float*)d_in[14];
  const float* atom_b2  = (const float*)d_in[15];
  const float* bond_w1  = (const float*)d_in[16];
  const float* bond_b1  = (const float*)d_in[17];
  const float* bond_w2  = (const float*)d_in[18];
  const float* bond_b2  = (const float*)d_in[19];
  const float* rbond_w  = (const float*)d_in[20];
  const float* rbond_b  = (const float*)d_in[21];
  const float* wbond_w  = (const float*)d_in[22];
  const float* wbond_b  = (const float*)d_in[23];
  const int* agraph     = (const int*)d_in[24];
  const int* bgraph     = (const int*)d_in[25];
  const int* node2graph = (const int*)d_in[26];
  const int* emask      = (const int*)d_in[27];
  const int* vmask      = (const int*)d_in[28];
  const int* topo_step  = (const int*)d_in[29];
  const int* topo_bid   = (const int*)d_in[30];
  const int* topo_xid   = (const int*)d_in[31];
  const int* topo_label = (const int*)d_in[32];
  const int* atom_step  = (const int*)d_in[33];
  const int* atom_bid   = (const int*)d_in[34];
  const int* atom_xid   = (const int*)d_in[35];
  const int* atom_label = (const int*)d_in[36];
  const int* bond_step  = (const int*)d_in[37];
  const int* bond_bid   = (const int*)d_in[38];
  const int* bond_zid   = (const int*)d_in[39];
  const int* bond_atype = (const int*)d_in[40];
  const int* bond_label = (const int*)d_in[41];
  const int* bond_gs    = (const int*)d_in[42];

  char* wp = (char*)d_ws;
  auto alloc = [&](size_t bytes) -> char* {
    char* p = wp; wp += (bytes + 255) & ~(size_t)255; return p;
  };
  // ~208 MB total -> L3-resident
  u8*  preB    = (u8*)alloc((size_t)NE * 256);            // fp8
  u8*  hu1B    = (u8*)alloc((size_t)NE * 256);            // fp8
  u16* foB     = (u16*)alloc((size_t)NN * 256 * 2);       // bf16
  float* gvec  = (float*)alloc((size_t)TT * BATCH * 256 * 4);
  u16* Wh_t    = (u16*)alloc(256 * 256 * 2);
  u16* Uh_t    = (u16*)alloc(256 * 256 * 2);
  u16* Wo1_t   = (u16*)alloc(256 * 256 * 2);
  u16* Wo2_t   = (u16*)alloc(256 * 256 * 2);
  u16* tw1_t   = (u16*)alloc(256 * 544 * 2);
  u16* aw1_t   = (u16*)alloc(256 * 544 * 2);
  u16* bw1_t   = (u16*)alloc(256 * 800 * 2);
  u16* rw_t    = (u16*)alloc(256 * 320 * 2);
  u16* ww_t    = (u16*)alloc(256 * 288 * 2);
  u16* w2c     = (u16*)alloc(3 * 64 * 256 * 2);
  float* b2c   = (float*)alloc(192 * 4);
  u16* tva     = (u16*)alloc((size_t)(PT + PA) * 544 * 2);
  u16* bv      = (u16*)alloc((size_t)PB * 800 * 2);
  u16* wbin    = (u16*)alloc((size_t)PB * 288 * 2);
  u16* rbin    = (u16*)alloc((size_t)PB * 320 * 2);
  u16* wb      = (u16*)alloc((size_t)PB * 256 * 2);
  u16* hid_all = (u16*)alloc((size_t)PALL * 256 * 2);
  float* logitsL = (float*)alloc((size_t)PALL * 64 * 4);
  u8*  T1      = (u8*)alloc((size_t)TB * NE * 256);       // fp8, 46 MB
  u8*  T2      = (u8*)alloc((size_t)TB * NE * 256);       // fp8, 46 MB
  u16* nodeB   = (u16*)alloc((size_t)TB * NN * 256 * 2);  // bf16, 46 MB
  u16* tv      = tva;
  u16* av      = tva + (size_t)PT * 544;

  float* out = (float*)d_out;

  init_zero_kernel<<<1536, 256, 0, stream>>>(gvec, out);
  transpose_all_kernel<<<3520, 256, 0, stream>>>(W_h, U_h, W_o, topo_w1, atom_w1, bond_w1,
      rbond_w, wbond_w, Wh_t, Uh_t, Wo1_t, Wo2_t, tw1_t, aw1_t, bw1_t, rw_t, ww_t);
  build_w2c_kernel<<<192, 256, 0, stream>>>(topo_w2, topo_b2, atom_w2, atom_b2,
                                            bond_w2, bond_b2, w2c, b2c);

  // step-invariant precomputes
  gemm_n256_kernel<1, 1><<<(NE + 127) / 128, 512, 0, stream>>>(
      fmess, NE, Wh_t, preB, nullptr);                         // pre = fmess@W_h  (fp8)
  gemm_n256_kernel<1, 0><<<(NN + 127) / 128, 512, 0, stream>>>(
      fnode, NN, Wo1_t, foB, nullptr);                         // fo = fnode@Wo1  (bf16)
  gemm_n256_kernel<2, 1><<<(NE + 127) / 128, 512, 0, stream>>>(
      preB, NE, Uh_t, hu1B, b_h);                              // hu1 = h1@U_h    (fp8)

  for (int t0 = 0; t0 < TT; t0 += TB) {
    int Mtot = TB * NE;
    int fb = (Mtot + 127) / 128;
    // fused gather+GEMM depth chain (T1/T2 double buffer)
    fused_gg_kernel<1><<<fb, 512, 0, stream>>>(hu1B, preB, bgraph, emask, b_h, t0, Mtot,
                                               Uh_t, T1);
    fused_gg_kernel<0><<<fb, 512, 0, stream>>>(T1, preB, bgraph, emask, b_h, t0, Mtot,
                                               Uh_t, T2);
    fused_gg_kernel<0><<<fb, 512, 0, stream>>>(T2, preB, bgraph, emask, b_h, t0, Mtot,
                                               Wo2_t, T1);
    // node = relu(fo + gather_n(T1) + b_o) * vm
    gather_n2_kernel<<<TB * NN / 8, 256, 0, stream>>>(T1, foB, agraph, emask, b_o,
                                                      vmask, t0, nodeB);
    // gvec + head scatter
    gvec_head_kernel<<<938 * TB + 1344, 256, 0, stream>>>(t0, nodeB, node2graph, gvec,
        topo_step, topo_xid, atom_step, atom_xid, bond_step, bond_zid,
        tv, av, bv, wbin);
  }

  // static head-input segments
  build_static_kernel<<<1344, 256, 0, stream>>>(gvec, src,
      topo_step, topo_bid, atom_step, atom_bid, bond_step, bond_bid,
      bond_label, bond_atype, tv, av, bv, wbin, rbin);

  // heads -> hid_all
  gemm_ta_kernel<<<dim3((PT + PA) / 128, 2), 256, 0, stream>>>(tva, tw1_t, aw1_t,
                                                               topo_b1, atom_b1, hid_all);
  gemm_bt_kernel<1><<<dim3(20, 2), 256, 0, stream>>>(wbin, 288, PB, ww_t, 288,
                                                     wb, 256, wbond_b);
  hist_kernel<<<640, 256, 0, stream>>>(wb, bond_gs, bond_label, rbin);
  gemm_bt_kernel<1><<<dim3(20, 2), 256, 0, stream>>>(rbin, 320, PB, rw_t, 320,
                                                     bv + 256, 800, rbond_b);
  gemm_bt_kernel<1><<<dim3(20, 2), 256, 0, stream>>>(bv, 800, PB, bw1_t, 800,
                                                     hid_all + (size_t)(PT + PA) * 256,
                                                     256, bond_b1);

  // losses: logits GEMM + finalize
  gemm_logits_kernel<<<PALL / 128, 256, 0, stream>>>(hid_all, w2c, b2c, logitsL);
  loss_finalize_kernel<<<PALL / 4, 256, 0, stream>>>(logitsL, topo_label, atom_label,
                                                     bond_label, out);
}